// Round 5
// baseline (5285.786 us; speedup 1.0000x reference)
//
#include <hip/hip_runtime.h>
#include <stdint.h>

// ---------------- problem constants ----------------
#define NN   10000      // nodes
#define NE   100000     // edges (= LSTM sequence length)
#define HD   128        // hidden_channels
#define G4   1024       // 4 * lstm hidden (gates)
#define KIN0 258        // 2H + 2
#define KP0  288        // KIN0 padded to multiple of 32
#define MPAD 100096     // NE padded to multiple of 128 (782 tiles)
#define BN_EPS 1e-5f

// chunked scan: 256 chunks (1 CU each), 64-step warmup.
#define CHUNKS 256
#define CLEN   391      // 256*391 = 100096 >= NE
#define WARM   64
#define TS     16       // steps per fused tile

using short8 = __attribute__((ext_vector_type(8))) short;
using half8  = __attribute__((ext_vector_type(8))) _Float16;
using f32x4  = __attribute__((ext_vector_type(4))) float;

// ---------------- helpers ----------------
__device__ __forceinline__ unsigned short f2h(float f){
  _Float16 h = (_Float16)f; return __builtin_bit_cast(unsigned short, h);
}
__device__ __forceinline__ float h2f(unsigned short u){
  return (float)__builtin_bit_cast(_Float16, u);
}
__device__ __forceinline__ float sigm(float x){
  x = fminf(fmaxf(x, -30.f), 30.f);
  return 1.f / (1.f + __expf(-x));
}
__device__ __forceinline__ float tanh_(float x){
  float xx = fminf(fmaxf(x, -15.f), 15.f);
  float e = __expf(2.f * xx);
  return (e - 1.f) / (e + 1.f);
}
__device__ __forceinline__ int sdot4(int a, int b, int c){
#if __has_builtin(__builtin_amdgcn_sdot4)
  return __builtin_amdgcn_sdot4(a, b, c, false);
#else
  return c + (int)((signed char)(a & 0xff))        * (int)((signed char)(b & 0xff))
           + (int)((signed char)((a >> 8) & 0xff)) * (int)((signed char)((b >> 8) & 0xff))
           + (int)((signed char)((a >> 16) & 0xff))* (int)((signed char)((b >> 16) & 0xff))
           + (int)((signed char)((a >> 24) & 0xff))* (int)((signed char)((b >> 24) & 0xff));
#endif
}

// ---------------- small utility kernels ----------------
__global__ void k_zero(float* p, long n){
  long i = (long)blockIdx.x * blockDim.x + threadIdx.x;
  long st = (long)gridDim.x * blockDim.x;
  for (; i < n; i += st) p[i] = 0.f;
}

__global__ void k_deg(const int* __restrict__ col, float* __restrict__ deg){
  int e = blockIdx.x * blockDim.x + threadIdx.x;
  if (e < NE) atomicAdd(&deg[col[e]], 1.0f);
}

__global__ void k_dinv(const float* __restrict__ deg, float* __restrict__ dinv){
  int v = blockIdx.x * blockDim.x + threadIdx.x;
  if (v < NN) dinv[v] = rsqrtf(deg[v] + 1.0f);   // +1 = self loop
}

__global__ void k_gcn1(const int* __restrict__ row, const int* __restrict__ col,
                       const float* __restrict__ x, const float* __restrict__ dinv,
                       float* __restrict__ s){
  int i = blockIdx.x * blockDim.x + threadIdx.x;
  if (i < NE){
    int r = row[i], c = col[i];
    atomicAdd(&s[c], dinv[r] * dinv[c] * x[r]);
  } else if (i < NE + NN){
    int v = i - NE;
    atomicAdd(&s[v], dinv[v] * dinv[v] * x[v]);
  }
}

__global__ void k_h1(const float* __restrict__ s, const float* __restrict__ W1,
                     const float* __restrict__ b1, const float* __restrict__ g1,
                     const float* __restrict__ be1, const float* __restrict__ rm1,
                     const float* __restrict__ rv1, float* __restrict__ h1){
  int idx = blockIdx.x * blockDim.x + threadIdx.x;
  if (idx >= NN * HD) return;
  int v = idx >> 7, h = idx & 127;
  float val = s[v] * W1[h] + b1[h];
  val = (val - rm1[h]) * rsqrtf(rv1[h] + BN_EPS) * g1[h] + be1[h];
  h1[idx] = fmaxf(val, 0.f);
}

// lin2 = h1 @ W2 ([NN,128] @ [128,128]); W2 staged fp16 in LDS
__global__ void k_lin2(const float* __restrict__ h1, const float* __restrict__ W2,
                       float* __restrict__ lin2){
  __shared__ unsigned short w[HD * HD];
  __shared__ float xr[HD];
  int t = threadIdx.x;                       // 128 threads
  for (int i = t; i < HD * HD; i += HD) w[i] = f2h(W2[i]);
  __syncthreads();
  for (int v = blockIdx.x; v < NN; v += gridDim.x){
    xr[t] = h1[v * HD + t];
    __syncthreads();
    float a = 0.f;
    #pragma unroll 8
    for (int k = 0; k < HD; ++k) a += xr[k] * h2f(w[k * HD + t]);
    lin2[v * HD + t] = a;
    __syncthreads();
  }
}

__global__ void k_gcn2(const int* __restrict__ row, const int* __restrict__ col,
                       const float* __restrict__ dinv, const float* __restrict__ lin2,
                       float* __restrict__ acc){
  long total = (long)NE * 32;
  long i = (long)blockIdx.x * blockDim.x + threadIdx.x;
  long st = (long)gridDim.x * blockDim.x;
  for (; i < total; i += st){
    int e = (int)(i >> 5), q = (int)(i & 31);
    int r = row[e], c = col[e];
    float nrm = dinv[r] * dinv[c];
    int hb = q * 4;
    #pragma unroll
    for (int j = 0; j < 4; ++j)
      atomicAdd(&acc[(long)c * HD + hb + j], lin2[(long)r * HD + hb + j] * nrm);
  }
}

__global__ void k_h2(const float* __restrict__ acc, const float* __restrict__ lin2,
                     const float* __restrict__ dinv, const float* __restrict__ b2,
                     const float* __restrict__ g2, const float* __restrict__ be2,
                     const float* __restrict__ rm2, const float* __restrict__ rv2,
                     unsigned short* __restrict__ h2h){
  int idx = blockIdx.x * blockDim.x + threadIdx.x;
  if (idx >= NN * HD) return;
  int v = idx >> 7, h = idx & 127;
  float val = acc[idx] + lin2[idx] * dinv[v] * dinv[v] + b2[h];
  val = (val - rm2[h]) * rsqrtf(rv2[h] + BN_EPS) * g2[h] + be2[h];
  h2h[idx] = f2h(fmaxf(val, 0.f));
}

// pack fp32 [rows][kin] -> fp16 [rows][kpad] (zero pad)
__global__ void k_packW(const float* __restrict__ W, int rows, int kin, int kpad,
                        unsigned short* __restrict__ out){
  long idx = (long)blockIdx.x * blockDim.x + threadIdx.x;
  if (idx >= (long)rows * kpad) return;
  int r = (int)(idx / kpad), k = (int)(idx % kpad);
  out[idx] = (k < kin) ? f2h(W[(long)r * kin + k]) : (unsigned short)0;
}

__global__ void k_bias(const float* a, const float* b, float* o, int n){
  int i = blockIdx.x * blockDim.x + threadIdx.x;
  if (i < n) o[i] = a[i] + b[i];
}

__global__ void k_packlw1(const float* __restrict__ lw1, unsigned short* __restrict__ out){
  int idx = blockIdx.x * blockDim.x + threadIdx.x;
  if (idx >= 128 * 256) return;
  int j = idx >> 8, k = idx & 255;
  out[idx] = f2h(lw1[k * 128 + j]);
}

// ---- Whh quantization: W = s*(p1 + nib/16); p1 int8; nib SIGNED int4 (two's compl).
__global__ void k_quant(const float* __restrict__ Whh, int* __restrict__ wp1,
                        int* __restrict__ wp2, float* __restrict__ srow){
  __shared__ unsigned char nib[256];
  int r = blockIdx.x;          // 1024 rows
  int l = threadIdx.x;         // 64 threads (one wave)
  float w0 = Whh[(long)r * 256 + l * 4 + 0];
  float w1 = Whh[(long)r * 256 + l * 4 + 1];
  float w2 = Whh[(long)r * 256 + l * 4 + 2];
  float w3 = Whh[(long)r * 256 + l * 4 + 3];
  float m = fmaxf(fmaxf(fabsf(w0), fabsf(w1)), fmaxf(fabsf(w2), fabsf(w3)));
  #pragma unroll
  for (int off = 32; off; off >>= 1) m = fmaxf(m, __shfl_xor(m, off, 64));
  float inv = (m > 0.f) ? 127.f / m : 0.f;
  float wv[4] = {w0, w1, w2, w3};
  int p1 = 0;
  #pragma unroll
  for (int j = 0; j < 4; ++j){
    float tq = wv[j] * inv;
    int q = __float2int_rn(tq);
    p1 |= (q & 255) << (8 * j);
    int pn = __float2int_rn((tq - (float)q) * 16.f);
    pn = min(max(pn, -8), 7);                        // SIGNED nibble
    nib[l * 4 + j] = (unsigned char)(pn & 0xF);
  }
  wp1[l * G4 + r] = p1;
  if (l == 0) srow[r] = m / 127.f;
  __syncthreads();
  if (l < 32){
    int base = l * 8;
    unsigned wq = 0;
    #pragma unroll
    for (int k = 0; k < 4; ++k) wq |= (unsigned)(nib[base + k]     & 0xF) << (8 * k);
    #pragma unroll
    for (int k = 0; k < 4; ++k) wq |= (unsigned)(nib[base + 4 + k] & 0xF) << (8 * k + 4);
    wp2[l * G4 + r] = (int)wq;
  }
}

// ---------------- fp16 MFMA GEMM (MLP head): C = A@B^T + bias, opt relu ----
__global__ __launch_bounds__(256)
void k_gemm_bt(const unsigned short* __restrict__ A, const unsigned short* __restrict__ B,
               const float* __restrict__ bias, unsigned short* __restrict__ C,
               int K, int Nout, int relu){
  __shared__ unsigned short As[128][40];
  __shared__ unsigned short Bs[128][40];
  const int tid = threadIdx.x;
  const int w = tid >> 6, l = tid & 63;
  const int m0 = blockIdx.x * 128, n0 = blockIdx.y * 128;
  const int wm = (w >> 1) * 64, wn = (w & 1) * 64;
  const int lrow = tid >> 1, lseg = tid & 1;
  const int mr = l & 15, kc = (l >> 4) * 8;

  f32x4 acc[4][4];
  #pragma unroll
  for (int i = 0; i < 4; ++i)
    #pragma unroll
    for (int j = 0; j < 4; ++j) acc[i][j] = (f32x4){0.f, 0.f, 0.f, 0.f};

  for (int k0 = 0; k0 < K; k0 += 32){
    const unsigned short* ap = A + (long)(m0 + lrow) * K + k0 + lseg * 16;
    const unsigned short* bp = B + (long)(n0 + lrow) * K + k0 + lseg * 16;
    *(short8*)&As[lrow][lseg * 16 + 0] = *(const short8*)(ap + 0);
    *(short8*)&As[lrow][lseg * 16 + 8] = *(const short8*)(ap + 8);
    *(short8*)&Bs[lrow][lseg * 16 + 0] = *(const short8*)(bp + 0);
    *(short8*)&Bs[lrow][lseg * 16 + 8] = *(const short8*)(bp + 8);
    __syncthreads();
    half8 af[4], bf[4];
    #pragma unroll
    for (int i = 0; i < 4; ++i){
      af[i] = __builtin_bit_cast(half8, *(const short8*)&As[wm + i * 16 + mr][kc]);
      bf[i] = __builtin_bit_cast(half8, *(const short8*)&Bs[wn + i * 16 + mr][kc]);
    }
    #pragma unroll
    for (int i = 0; i < 4; ++i)
      #pragma unroll
      for (int j = 0; j < 4; ++j)
        acc[i][j] = __builtin_amdgcn_mfma_f32_16x16x32_f16(af[i], bf[j], acc[i][j], 0, 0, 0);
    __syncthreads();
  }
  const int cr = (l >> 4) * 4, cc = l & 15;
  #pragma unroll
  for (int i = 0; i < 4; ++i)
    #pragma unroll
    for (int j = 0; j < 4; ++j){
      int colg = n0 + wn + j * 16 + cc;
      float bs = bias ? bias[colg] : 0.f;
      #pragma unroll
      for (int r = 0; r < 4; ++r){
        float v = acc[i][j][r] + bs;
        if (relu) v = fmaxf(v, 0.f);
        long rowg = m0 + wm + i * 16 + cr + r;
        C[rowg * Nout + colg] = f2h(v);
      }
    }
}

// ---------------- fused GEMM + chunked LSTM scan, 512 threads ----------------
// thread t: unit u = t&255, gate-pair gp = t>>8.
// amdgpu_waves_per_eu(2,2): pin occupancy target to 2 waves/SIMD -> 256-VGPR
// budget, so the 192-dword weight set stays in registers (R4: compiler chose
// 128 VGPR for a phantom 2nd block -> ~120 dwords/thread spilled, FETCH 700MB).
__global__ __launch_bounds__(512) __attribute__((amdgpu_waves_per_eu(2, 2)))
void k_fscan(const unsigned short* __restrict__ xsrc,
             const int* __restrict__ row, const int* __restrict__ col,
             const float* __restrict__ attr,
             const unsigned short* __restrict__ Wb, const float* __restrict__ bias,
             int Kp, int mode,
             const int* __restrict__ wp1, const int* __restrict__ wp2,
             const float* __restrict__ srow,
             unsigned short* __restrict__ sout){
  const int t = threadIdx.x;                 // 0..511
  const int start = blockIdx.x * CLEN;
  if (start >= NE) return;
  const int end = min(start + CLEN, NE);
  const int w0 = max(start - WARM, 0);

  const int u  = t & 255;
  const int gp = t >> 8;

  __shared__ unsigned short xs[TS][312];     // stride 156 dw == 28 mod 32 -> 2-way reads
  __shared__ unsigned short ps[TS][1030];    // stride 515 dw == 3 mod 32 -> spread writes
  __shared__ float zb[4][256];
  __shared__ __align__(16) int hq1[64];
  __shared__ __align__(16) int hq2[64];

  // recurrent weights (2 gates) -> registers (192 VGPRs)
  int p1r[2][64];
  int p2r[2][32];
  #pragma unroll
  for (int g = 0; g < 2; ++g){
    const int G = gp * 2 + g;
    const int* q1p = wp1 + G * 256 + u;
    #pragma unroll
    for (int d = 0; d < 64; ++d) p1r[g][d] = q1p[d * G4];
    const int* q2p = wp2 + G * 256 + u;
    #pragma unroll
    for (int m = 0; m < 32; ++m) p2r[g][m] = q2p[m * G4];
  }
  float k1[2];
  #pragma unroll
  for (int g = 0; g < 2; ++g) k1[g] = srow[(gp * 2 + g) * 256 + u] * (1.f / 127.f);

  if (t < 64){ hq1[t] = 0; hq2[t] = 0; }
  float cst = 0.f;

  const int l = t & 63, w = t >> 6;          // wave 0..7
  const int mr = l & 15, kc = (l >> 4) * 8;
  const int sA = t >> 5, segA = t & 31;      // phase-A mapping

  for (int tile = w0; tile < end; tile += TS){
    // ---- phase A: gather x-tile (one short8 per thread)
    if (mode == 0){
      int e = tile + sA;
      if (e < NE){
        int rr = row[e], cc2 = col[e];
        const unsigned short* src = (segA < 16) ? (xsrc + rr * HD + segA * 8)
                                                : (xsrc + cc2 * HD + (segA - 16) * 8);
        *(short8*)&xs[sA][segA * 8] = *(const short8*)src;
      }
      if (t < TS){
        int e2 = tile + t;
        if (e2 < NE){
          xs[t][256] = f2h(attr[(long)e2 * 2]);
          xs[t][257] = f2h(attr[(long)e2 * 2 + 1]);
        } else { xs[t][256] = 0; xs[t][257] = 0; }
        for (int k2 = 258; k2 < KP0; ++k2) xs[t][k2] = 0;
      }
    } else {
      int e = tile + sA;                     // e < NE+15 < MPAD: xsrc rows exist
      *(short8*)&xs[sA][segA * 8] = *(const short8*)(xsrc + (long)e * 256 + segA * 8);
    }
    __syncthreads();                         // xs ready
    // ---- phase B: ps = xs @ Wb^T + bias (8 waves x 2 gate-blocks of 64)
    #pragma unroll
    for (int pp = 0; pp < 2; ++pp){
      f32x4 a0 = (f32x4){0.f,0.f,0.f,0.f};
      f32x4 a1 = (f32x4){0.f,0.f,0.f,0.f};
      f32x4 a2 = (f32x4){0.f,0.f,0.f,0.f};
      f32x4 a3 = (f32x4){0.f,0.f,0.f,0.f};
      const int gb = w * 128 + pp * 64 + mr;
      for (int k0 = 0; k0 < Kp; k0 += 32){
        half8 af = __builtin_bit_cast(half8, *(const short8*)&xs[mr][k0 + kc]);
        half8 b0 = __builtin_bit_cast(half8, *(const short8*)(Wb + (long)(gb     ) * Kp + k0 + kc));
        half8 b1 = __builtin_bit_cast(half8, *(const short8*)(Wb + (long)(gb + 16) * Kp + k0 + kc));
        half8 b2 = __builtin_bit_cast(half8, *(const short8*)(Wb + (long)(gb + 32) * Kp + k0 + kc));
        half8 b3 = __builtin_bit_cast(half8, *(const short8*)(Wb + (long)(gb + 48) * Kp + k0 + kc));
        a0 = __builtin_amdgcn_mfma_f32_16x16x32_f16(af, b0, a0, 0, 0, 0);
        a1 = __builtin_amdgcn_mfma_f32_16x16x32_f16(af, b1, a1, 0, 0, 0);
        a2 = __builtin_amdgcn_mfma_f32_16x16x32_f16(af, b2, a2, 0, 0, 0);
        a3 = __builtin_amdgcn_mfma_f32_16x16x32_f16(af, b3, a3, 0, 0, 0);
      }
      const int sr_ = (l >> 4) * 4;
      #pragma unroll
      for (int r = 0; r < 4; ++r){
        ps[sr_ + r][gb     ] = f2h(a0[r] + bias[gb     ]);
        ps[sr_ + r][gb + 16] = f2h(a1[r] + bias[gb + 16]);
        ps[sr_ + r][gb + 32] = f2h(a2[r] + bias[gb + 32]);
        ps[sr_ + r][gb + 48] = f2h(a3[r] + bias[gb + 48]);
      }
    }
    __syncthreads();                         // ps ready
    // ---- phase C: serial recurrence
    const int smax = min(TS, end - tile);
    for (int s = 0; s < smax; ++s){
      float pv0 = h2f(ps[s][(gp * 2 + 0) * 256 + u]);
      float pv1 = h2f(ps[s][(gp * 2 + 1) * 256 + u]);
      const int4* q1v = (const int4*)hq1;
      const int4* q2v = (const int4*)hq2;
      int A0=0, B0=0, C0=0, A1=0, B1=0, C1=0;
      #pragma unroll
      for (int mm = 0; mm < 16; ++mm){
        int4 qa = q1v[mm];
        int4 qb = q2v[mm];
        A0 = sdot4(qa.x, p1r[0][4*mm+0], A0); A0 = sdot4(qa.y, p1r[0][4*mm+1], A0);
        A0 = sdot4(qa.z, p1r[0][4*mm+2], A0); A0 = sdot4(qa.w, p1r[0][4*mm+3], A0);
        B0 = sdot4(qb.x, p1r[0][4*mm+0], B0); B0 = sdot4(qb.y, p1r[0][4*mm+1], B0);
        B0 = sdot4(qb.z, p1r[0][4*mm+2], B0); B0 = sdot4(qb.w, p1r[0][4*mm+3], B0);
        { int wA = p2r[0][2*mm], wB = p2r[0][2*mm+1];
          C0 = sdot4((wA << 4) & 0xf0f0f0f0, qa.x, C0);
          C0 = sdot4( wA       & 0xf0f0f0f0, qa.y, C0);
          C0 = sdot4((wB << 4) & 0xf0f0f0f0, qa.z, C0);
          C0 = sdot4( wB       & 0xf0f0f0f0, qa.w, C0); }
        A1 = sdot4(qa.x, p1r[1][4*mm+0], A1); A1 = sdot4(qa.y, p1r[1][4*mm+1], A1);
        A1 = sdot4(qa.z, p1r[1][4*mm+2], A1); A1 = sdot4(qa.w, p1r[1][4*mm+3], A1);
        B1 = sdot4(qb.x, p1r[1][4*mm+0], B1); B1 = sdot4(qb.y, p1r[1][4*mm+1], B1);
        B1 = sdot4(qb.z, p1r[1][4*mm+2], B1); B1 = sdot4(qb.w, p1r[1][4*mm+3], B1);
        { int wA = p2r[1][2*mm], wB = p2r[1][2*mm+1];
          C1 = sdot4((wA << 4) & 0xf0f0f0f0, qa.x, C1);
          C1 = sdot4( wA       & 0xf0f0f0f0, qa.y, C1);
          C1 = sdot4((wB << 4) & 0xf0f0f0f0, qa.z, C1);
          C1 = sdot4( wB       & 0xf0f0f0f0, qa.w, C1); }
      }
      float z0 = pv0 + k1[0] * ((float)A0 + (float)B0 * (1.f/127.f) + (float)C0 * (1.f/256.f));
      float z1 = pv1 + k1[1] * ((float)A1 + (float)B1 * (1.f/127.f) + (float)C1 * (1.f/256.f));
      zb[gp * 2 + 0][u] = z0;
      zb[gp * 2 + 1][u] = z1;
      __syncthreads();                       // zb ready; hq reads done
      if (t < 256){
        float ig = sigm(zb[0][t]), fg = sigm(zb[1][t]);
        float gg = tanh_(zb[2][t]), og = sigm(zb[3][t]);
        cst = fg * cst + ig * gg;
        float hh = og * tanh_(cst);
        int step = tile + s;
        if (step >= start) sout[(long)step * 256 + t] = f2h(hh);
        float h127 = hh * 127.f;
        int q1 = __float2int_rn(h127);
        int q2 = __float2int_rn((h127 - (float)q1) * 127.f);
        ((signed char*)hq1)[t] = (signed char)q1;
        ((signed char*)hq2)[t] = (signed char)q2;
      }
      __syncthreads();                       // hq ready for next step
    }
  }
}

// final: out[e] = hid[e] . lw2 + lb2   (wave per edge)
__global__ void k_final(const unsigned short* __restrict__ hid, const float* __restrict__ lw2,
                        const float* __restrict__ lb2, float* __restrict__ out){
  int wid = (blockIdx.x * blockDim.x + threadIdx.x) >> 6;
  int l = threadIdx.x & 63;
  int nw = (gridDim.x * blockDim.x) >> 6;
  for (int e = wid; e < NE; e += nw){
    float a = h2f(hid[(long)e * HD + l]) * lw2[l]
            + h2f(hid[(long)e * HD + 64 + l]) * lw2[64 + l];
    #pragma unroll
    for (int off = 32; off; off >>= 1) a += __shfl_down(a, off, 64);
    if (l == 0) out[e] = a + lb2[0];
  }
}

// ---------------- host ----------------
extern "C" void kernel_launch(void* const* d_in, const int* in_sizes, int n_in,
                              void* d_out, int out_size, void* d_ws, size_t ws_size,
                              hipStream_t stream) {
  const float* x    = (const float*)d_in[0];
  const int*   ei   = (const int*)d_in[1];
  const float* attr = (const float*)d_in[2];
  const float* W1   = (const float*)d_in[3];
  const float* b1   = (const float*)d_in[4];
  const float* g1   = (const float*)d_in[5];
  const float* be1  = (const float*)d_in[6];
  const float* rm1  = (const float*)d_in[7];
  const float* rv1  = (const float*)d_in[8];
  const float* W2   = (const float*)d_in[9];
  const float* b2   = (const float*)d_in[10];
  const float* g2   = (const float*)d_in[11];
  const float* be2  = (const float*)d_in[12];
  const float* rm2  = (const float*)d_in[13];
  const float* rv2  = (const float*)d_in[14];
  const float* Wih0 = (const float*)d_in[15];
  const float* Whh0 = (const float*)d_in[16];
  const float* bih0 = (const float*)d_in[17];
  const float* bhh0 = (const float*)d_in[18];
  const float* Wih1 = (const float*)d_in[19];
  const float* Whh1 = (const float*)d_in[20];
  const float* bih1 = (const float*)d_in[21];
  const float* bhh1 = (const float*)d_in[22];
  const float* lw1  = (const float*)d_in[23];
  const float* lb1  = (const float*)d_in[24];
  const float* lw2  = (const float*)d_in[25];
  const float* lb2  = (const float*)d_in[26];
  const int* row = ei;
  const int* col = ei + NE;
  float* out = (float*)d_out;
  (void)in_sizes; (void)n_in; (void)out_size;

  // ---- workspace carve (~107 MB total) ----
  char* p0 = (char*)d_ws;
  char* p = p0;
  auto take = [&](size_t bytes)->char*{
    char* r = p; p += (bytes + 255) & ~(size_t)255; return r;
  };
  int*   wp1_0 = (int*)take((size_t)64 * G4 * 4);
  int*   wp2_0 = (int*)take((size_t)32 * G4 * 4);
  float* sr0   = (float*)take((size_t)G4 * 4);
  int*   wp1_1 = (int*)take((size_t)64 * G4 * 4);
  int*   wp2_1 = (int*)take((size_t)32 * G4 * 4);
  float* sr1   = (float*)take((size_t)G4 * 4);
  float* bias0 = (float*)take((size_t)G4 * 4);
  float* bias1 = (float*)take((size_t)G4 * 4);
  unsigned short* Wb0  = (unsigned short*)take((size_t)G4 * KP0 * 2);
  unsigned short* Wb1  = (unsigned short*)take((size_t)G4 * 256 * 2);
  unsigned short* lw1T = (unsigned short*)take((size_t)128 * 256 * 2);
  unsigned short* h2h  = (unsigned short*)take((size_t)NN * HD * 2);
  unsigned short* s1   = (unsigned short*)take((size_t)MPAD * 256 * 2);
  unsigned short* s2   = (unsigned short*)take((size_t)MPAD * 256 * 2);
  size_t required = (size_t)(p - p0);
  unsigned short* hid = s1;          // s1 dead once fscan1 consumed it

  // GCN scratch aliases inside s2 (dead before fscan1 writes s2)
  char* q = (char*)s2;
  auto take2 = [&](size_t bytes)->char*{
    char* r = q; q += (bytes + 255) & ~(size_t)255; return r;
  };
  float* deg  = (float*)take2((size_t)NN * 4);
  float* sacc = (float*)take2((size_t)NN * 4);
  float* acc2 = (float*)take2((size_t)NN * HD * 4);
  size_t zfloats = (size_t)(q - (char*)deg) / 4;
  float* dinv = (float*)take2((size_t)NN * 4);
  float* h1   = (float*)take2((size_t)NN * HD * 4);
  float* lin2 = (float*)take2((size_t)NN * HD * 4);

  if (ws_size < required){
    k_zero<<<256, 256, 0, stream>>>(out, (long)NE);
    return;
  }

  // --- GCN ---
  k_zero<<<2048, 256, 0, stream>>>(deg, (long)zfloats);
  k_deg<<<(NE + 255) / 256, 256, 0, stream>>>(col, deg);
  k_dinv<<<(NN + 255) / 256, 256, 0, stream>>>(deg, dinv);
  k_gcn1<<<(NE + NN + 255) / 256, 256, 0, stream>>>(row, col, x, dinv, sacc);
  k_h1<<<(NN * HD) / 256, 256, 0, stream>>>(sacc, W1, b1, g1, be1, rm1, rv1, h1);
  k_lin2<<<640, 128, 0, stream>>>(h1, W2, lin2);
  k_gcn2<<<4096, 256, 0, stream>>>(row, col, dinv, lin2, acc2);
  k_h2<<<(NN * HD) / 256, 256, 0, stream>>>(acc2, lin2, dinv, b2, g2, be2, rm2, rv2, h2h);

  // --- weight packing / quantization ---
  k_packW<<<(G4 * KP0 + 255) / 256, 256, 0, stream>>>(Wih0, G4, KIN0, KP0, Wb0);
  k_bias<<<4, 256, 0, stream>>>(bih0, bhh0, bias0, G4);
  k_packW<<<(G4 * 256 + 255) / 256, 256, 0, stream>>>(Wih1, G4, 256, 256, Wb1);
  k_bias<<<4, 256, 0, stream>>>(bih1, bhh1, bias1, G4);
  k_packlw1<<<(128 * 256) / 256, 256, 0, stream>>>(lw1, lw1T);
  k_quant<<<G4, 64, 0, stream>>>(Whh0, wp1_0, wp2_0, sr0);
  k_quant<<<G4, 64, 0, stream>>>(Whh1, wp1_1, wp2_1, sr1);

  // --- LSTM layers (fused GEMM+scan, 512 threads) ---
  k_fscan<<<CHUNKS, 512, 0, stream>>>(h2h, row, col, attr, Wb0, bias0, KP0, 0,
                                      wp1_0, wp2_0, sr0, s1);
  k_fscan<<<CHUNKS, 512, 0, stream>>>(s1, nullptr, nullptr, nullptr, Wb1, bias1, 256, 1,
                                      wp1_1, wp2_1, sr1, s2);

  // --- MLP head ---
  k_gemm_bt<<<dim3(MPAD / 128, 1), 256, 0, stream>>>(s2, lw1T, lb1, hid, 256, HD, 1);
  k_final<<<512, 256, 0, stream>>>(hid, lw2, lb2, out);
}

// Round 6
// 4861.471 us; speedup vs baseline: 1.0873x; 1.0873x over previous
//
#include <hip/hip_runtime.h>
#include <stdint.h>

// ---------------- problem constants ----------------
#define NN   10000      // nodes
#define NE   100000     // edges (= LSTM sequence length)
#define HD   128        // hidden_channels
#define G4   1024       // 4 * lstm hidden (gates)
#define KIN0 258        // 2H + 2
#define KP0  288        // KIN0 padded to multiple of 32
#define MPAD 100096     // NE padded to multiple of 128 (782 tiles)
#define BN_EPS 1e-5f

// chunked scan: 256 chunks (1 CU each), 64-step warmup.
#define CHUNKS 256
#define CLEN   391      // 256*391 = 100096 >= NE
#define WARM   64
#define TS     16       // steps per fused tile

using short8 = __attribute__((ext_vector_type(8))) short;
using half8  = __attribute__((ext_vector_type(8))) _Float16;
using f32x4  = __attribute__((ext_vector_type(4))) float;

// ---------------- helpers ----------------
__device__ __forceinline__ unsigned short f2h(float f){
  _Float16 h = (_Float16)f; return __builtin_bit_cast(unsigned short, h);
}
__device__ __forceinline__ float h2f(unsigned short u){
  return (float)__builtin_bit_cast(_Float16, u);
}
__device__ __forceinline__ float sigm(float x){
  x = fminf(fmaxf(x, -30.f), 30.f);
  return 1.f / (1.f + __expf(-x));
}
__device__ __forceinline__ float tanh_(float x){
  float xx = fminf(fmaxf(x, -15.f), 15.f);
  float e = __expf(2.f * xx);
  return (e - 1.f) / (e + 1.f);
}
__device__ __forceinline__ int sdot4(int a, int b, int c){
#if __has_builtin(__builtin_amdgcn_sdot4)
  return __builtin_amdgcn_sdot4(a, b, c, false);
#else
  return c + (int)((signed char)(a & 0xff))        * (int)((signed char)(b & 0xff))
           + (int)((signed char)((a >> 8) & 0xff)) * (int)((signed char)((b >> 8) & 0xff))
           + (int)((signed char)((a >> 16) & 0xff))* (int)((signed char)((b >> 16) & 0xff))
           + (int)((signed char)((a >> 24) & 0xff))* (int)((signed char)((b >> 24) & 0xff));
#endif
}

// ---------------- small utility kernels ----------------
__global__ void k_zero(float* p, long n){
  long i = (long)blockIdx.x * blockDim.x + threadIdx.x;
  long st = (long)gridDim.x * blockDim.x;
  for (; i < n; i += st) p[i] = 0.f;
}

__global__ void k_deg(const int* __restrict__ col, float* __restrict__ deg){
  int e = blockIdx.x * blockDim.x + threadIdx.x;
  if (e < NE) atomicAdd(&deg[col[e]], 1.0f);
}

__global__ void k_dinv(const float* __restrict__ deg, float* __restrict__ dinv){
  int v = blockIdx.x * blockDim.x + threadIdx.x;
  if (v < NN) dinv[v] = rsqrtf(deg[v] + 1.0f);   // +1 = self loop
}

__global__ void k_gcn1(const int* __restrict__ row, const int* __restrict__ col,
                       const float* __restrict__ x, const float* __restrict__ dinv,
                       float* __restrict__ s){
  int i = blockIdx.x * blockDim.x + threadIdx.x;
  if (i < NE){
    int r = row[i], c = col[i];
    atomicAdd(&s[c], dinv[r] * dinv[c] * x[r]);
  } else if (i < NE + NN){
    int v = i - NE;
    atomicAdd(&s[v], dinv[v] * dinv[v] * x[v]);
  }
}

__global__ void k_h1(const float* __restrict__ s, const float* __restrict__ W1,
                     const float* __restrict__ b1, const float* __restrict__ g1,
                     const float* __restrict__ be1, const float* __restrict__ rm1,
                     const float* __restrict__ rv1, float* __restrict__ h1){
  int idx = blockIdx.x * blockDim.x + threadIdx.x;
  if (idx >= NN * HD) return;
  int v = idx >> 7, h = idx & 127;
  float val = s[v] * W1[h] + b1[h];
  val = (val - rm1[h]) * rsqrtf(rv1[h] + BN_EPS) * g1[h] + be1[h];
  h1[idx] = fmaxf(val, 0.f);
}

// lin2 = h1 @ W2 ([NN,128] @ [128,128]); W2 staged fp16 in LDS
__global__ void k_lin2(const float* __restrict__ h1, const float* __restrict__ W2,
                       float* __restrict__ lin2){
  __shared__ unsigned short w[HD * HD];
  __shared__ float xr[HD];
  int t = threadIdx.x;                       // 128 threads
  for (int i = t; i < HD * HD; i += HD) w[i] = f2h(W2[i]);
  __syncthreads();
  for (int v = blockIdx.x; v < NN; v += gridDim.x){
    xr[t] = h1[v * HD + t];
    __syncthreads();
    float a = 0.f;
    #pragma unroll 8
    for (int k = 0; k < HD; ++k) a += xr[k] * h2f(w[k * HD + t]);
    lin2[v * HD + t] = a;
    __syncthreads();
  }
}

__global__ void k_gcn2(const int* __restrict__ row, const int* __restrict__ col,
                       const float* __restrict__ dinv, const float* __restrict__ lin2,
                       float* __restrict__ acc){
  long total = (long)NE * 32;
  long i = (long)blockIdx.x * blockDim.x + threadIdx.x;
  long st = (long)gridDim.x * blockDim.x;
  for (; i < total; i += st){
    int e = (int)(i >> 5), q = (int)(i & 31);
    int r = row[e], c = col[e];
    float nrm = dinv[r] * dinv[c];
    int hb = q * 4;
    #pragma unroll
    for (int j = 0; j < 4; ++j)
      atomicAdd(&acc[(long)c * HD + hb + j], lin2[(long)r * HD + hb + j] * nrm);
  }
}

__global__ void k_h2(const float* __restrict__ acc, const float* __restrict__ lin2,
                     const float* __restrict__ dinv, const float* __restrict__ b2,
                     const float* __restrict__ g2, const float* __restrict__ be2,
                     const float* __restrict__ rm2, const float* __restrict__ rv2,
                     unsigned short* __restrict__ h2h){
  int idx = blockIdx.x * blockDim.x + threadIdx.x;
  if (idx >= NN * HD) return;
  int v = idx >> 7, h = idx & 127;
  float val = acc[idx] + lin2[idx] * dinv[v] * dinv[v] + b2[h];
  val = (val - rm2[h]) * rsqrtf(rv2[h] + BN_EPS) * g2[h] + be2[h];
  h2h[idx] = f2h(fmaxf(val, 0.f));
}

// pack fp32 [rows][kin] -> fp16 [rows][kpad] (zero pad)
__global__ void k_packW(const float* __restrict__ W, int rows, int kin, int kpad,
                        unsigned short* __restrict__ out){
  long idx = (long)blockIdx.x * blockDim.x + threadIdx.x;
  if (idx >= (long)rows * kpad) return;
  int r = (int)(idx / kpad), k = (int)(idx % kpad);
  out[idx] = (k < kin) ? f2h(W[(long)r * kin + k]) : (unsigned short)0;
}

__global__ void k_bias(const float* a, const float* b, float* o, int n){
  int i = blockIdx.x * blockDim.x + threadIdx.x;
  if (i < n) o[i] = a[i] + b[i];
}

__global__ void k_packlw1(const float* __restrict__ lw1, unsigned short* __restrict__ out){
  int idx = blockIdx.x * blockDim.x + threadIdx.x;
  if (idx >= 128 * 256) return;
  int j = idx >> 8, k = idx & 255;
  out[idx] = f2h(lw1[k * 128 + j]);
}

// ---- Whh quantization: W = s*(p1 + nib/16); p1 int8; nib SIGNED int4 (two's compl).
__global__ void k_quant(const float* __restrict__ Whh, int* __restrict__ wp1,
                        int* __restrict__ wp2, float* __restrict__ srow){
  __shared__ unsigned char nib[256];
  int r = blockIdx.x;          // 1024 rows
  int l = threadIdx.x;         // 64 threads (one wave)
  float w0 = Whh[(long)r * 256 + l * 4 + 0];
  float w1 = Whh[(long)r * 256 + l * 4 + 1];
  float w2 = Whh[(long)r * 256 + l * 4 + 2];
  float w3 = Whh[(long)r * 256 + l * 4 + 3];
  float m = fmaxf(fmaxf(fabsf(w0), fabsf(w1)), fmaxf(fabsf(w2), fabsf(w3)));
  #pragma unroll
  for (int off = 32; off; off >>= 1) m = fmaxf(m, __shfl_xor(m, off, 64));
  float inv = (m > 0.f) ? 127.f / m : 0.f;
  float wv[4] = {w0, w1, w2, w3};
  int p1 = 0;
  #pragma unroll
  for (int j = 0; j < 4; ++j){
    float tq = wv[j] * inv;
    int q = __float2int_rn(tq);
    p1 |= (q & 255) << (8 * j);
    int pn = __float2int_rn((tq - (float)q) * 16.f);
    pn = min(max(pn, -8), 7);                        // SIGNED nibble
    nib[l * 4 + j] = (unsigned char)(pn & 0xF);
  }
  wp1[l * G4 + r] = p1;
  if (l == 0) srow[r] = m / 127.f;
  __syncthreads();
  if (l < 32){
    int base = l * 8;
    unsigned wq = 0;
    #pragma unroll
    for (int k = 0; k < 4; ++k) wq |= (unsigned)(nib[base + k]     & 0xF) << (8 * k);
    #pragma unroll
    for (int k = 0; k < 4; ++k) wq |= (unsigned)(nib[base + 4 + k] & 0xF) << (8 * k + 4);
    wp2[l * G4 + r] = (int)wq;
  }
}

// ---------------- fp16 MFMA GEMM (MLP head): C = A@B^T + bias, opt relu ----
__global__ __launch_bounds__(256)
void k_gemm_bt(const unsigned short* __restrict__ A, const unsigned short* __restrict__ B,
               const float* __restrict__ bias, unsigned short* __restrict__ C,
               int K, int Nout, int relu){
  __shared__ unsigned short As[128][40];
  __shared__ unsigned short Bs[128][40];
  const int tid = threadIdx.x;
  const int w = tid >> 6, l = tid & 63;
  const int m0 = blockIdx.x * 128, n0 = blockIdx.y * 128;
  const int wm = (w >> 1) * 64, wn = (w & 1) * 64;
  const int lrow = tid >> 1, lseg = tid & 1;
  const int mr = l & 15, kc = (l >> 4) * 8;

  f32x4 acc[4][4];
  #pragma unroll
  for (int i = 0; i < 4; ++i)
    #pragma unroll
    for (int j = 0; j < 4; ++j) acc[i][j] = (f32x4){0.f, 0.f, 0.f, 0.f};

  for (int k0 = 0; k0 < K; k0 += 32){
    const unsigned short* ap = A + (long)(m0 + lrow) * K + k0 + lseg * 16;
    const unsigned short* bp = B + (long)(n0 + lrow) * K + k0 + lseg * 16;
    *(short8*)&As[lrow][lseg * 16 + 0] = *(const short8*)(ap + 0);
    *(short8*)&As[lrow][lseg * 16 + 8] = *(const short8*)(ap + 8);
    *(short8*)&Bs[lrow][lseg * 16 + 0] = *(const short8*)(bp + 0);
    *(short8*)&Bs[lrow][lseg * 16 + 8] = *(const short8*)(bp + 8);
    __syncthreads();
    half8 af[4], bf[4];
    #pragma unroll
    for (int i = 0; i < 4; ++i){
      af[i] = __builtin_bit_cast(half8, *(const short8*)&As[wm + i * 16 + mr][kc]);
      bf[i] = __builtin_bit_cast(half8, *(const short8*)&Bs[wn + i * 16 + mr][kc]);
    }
    #pragma unroll
    for (int i = 0; i < 4; ++i)
      #pragma unroll
      for (int j = 0; j < 4; ++j)
        acc[i][j] = __builtin_amdgcn_mfma_f32_16x16x32_f16(af[i], bf[j], acc[i][j], 0, 0, 0);
    __syncthreads();
  }
  const int cr = (l >> 4) * 4, cc = l & 15;
  #pragma unroll
  for (int i = 0; i < 4; ++i)
    #pragma unroll
    for (int j = 0; j < 4; ++j){
      int colg = n0 + wn + j * 16 + cc;
      float bs = bias ? bias[colg] : 0.f;
      #pragma unroll
      for (int r = 0; r < 4; ++r){
        float v = acc[i][j][r] + bs;
        if (relu) v = fmaxf(v, 0.f);
        long rowg = m0 + wm + i * 16 + cr + r;
        C[rowg * Nout + colg] = f2h(v);
      }
    }
}

// ---------------- fused GEMM + chunked LSTM scan, 1024 threads ----------------
// thread t: gate row G = t>>8 (0..3), unit u = t&255 -> ONE gate row per thread.
// Weights/thread: p1[64] + p2[32] = 96 dwords -> phase-C live set ~125, fits the
// 128-VGPR budget at 4 waves/SIMD natively (R5: 192-dword set spilled at 128).
// __launch_bounds__(1024, 4): 16 waves = 4/SIMD = exactly 1 block/CU, cap 128.
// Phase B sub-blocked to 32 cols/wave (2 accs) to keep peak pressure <= ~122.
__global__ __launch_bounds__(1024, 4)
void k_fscan(const unsigned short* __restrict__ xsrc,
             const int* __restrict__ row, const int* __restrict__ col,
             const float* __restrict__ attr,
             const unsigned short* __restrict__ Wb, const float* __restrict__ bias,
             int Kp, int mode,
             const int* __restrict__ wp1, const int* __restrict__ wp2,
             const float* __restrict__ srow,
             unsigned short* __restrict__ sout){
  const int t = threadIdx.x;                 // 0..1023
  const int start = blockIdx.x * CLEN;
  if (start >= NE) return;
  const int end = min(start + CLEN, NE);
  const int w0 = max(start - WARM, 0);

  const int u = t & 255;
  const int G = t >> 8;                      // gate row 0..3

  __shared__ unsigned short xs[TS][312];     // stride 156 dw == 28 mod 32 -> 2-way reads
  __shared__ unsigned short ps[TS][1030];    // stride 515 dw == 3 mod 32 -> spread writes
  __shared__ float zb[4][256];
  __shared__ __align__(16) int hq1[64];
  __shared__ __align__(16) int hq2[64];

  // recurrent weights (1 gate row) -> 96 VGPRs
  int p1r[64];
  int p2r[32];
  {
    const int* q1p = wp1 + G * 256 + u;
    #pragma unroll
    for (int d = 0; d < 64; ++d) p1r[d] = q1p[d * G4];
    const int* q2p = wp2 + G * 256 + u;
    #pragma unroll
    for (int m = 0; m < 32; ++m) p2r[m] = q2p[m * G4];
  }
  const float k1 = srow[G * 256 + u] * (1.f / 127.f);

  if (t < 64){ hq1[t] = 0; hq2[t] = 0; }
  float cst = 0.f;

  const int l = t & 63, w = t >> 6;          // wave 0..15
  const int mr = l & 15, kc = (l >> 4) * 8;
  const int sA = (t & 511) >> 5, segA = t & 31;   // phase-A mapping (t<512 active)

  for (int tile = w0; tile < end; tile += TS){
    // ---- phase A: gather x-tile (threads < 512, one short8 each)
    if (mode == 0){
      if (t < 512){
        int e = tile + sA;
        if (e < NE){
          int rr = row[e], cc2 = col[e];
          const unsigned short* src = (segA < 16) ? (xsrc + rr * HD + segA * 8)
                                                  : (xsrc + cc2 * HD + (segA - 16) * 8);
          *(short8*)&xs[sA][segA * 8] = *(const short8*)src;
        }
      }
      if (t < TS){
        int e2 = tile + t;
        if (e2 < NE){
          xs[t][256] = f2h(attr[(long)e2 * 2]);
          xs[t][257] = f2h(attr[(long)e2 * 2 + 1]);
        } else { xs[t][256] = 0; xs[t][257] = 0; }
        for (int k2 = 258; k2 < KP0; ++k2) xs[t][k2] = 0;
      }
    } else {
      if (t < 512){
        int e = tile + sA;                   // e <= NE+14 < MPAD: rows exist
        *(short8*)&xs[sA][segA * 8] = *(const short8*)(xsrc + (long)e * 256 + segA * 8);
      }
    }
    __syncthreads();                         // xs ready
    // ---- phase B: ps = xs @ Wb^T + bias (16 waves x 2 sub-blocks of 32 cols)
    #pragma unroll
    for (int sub = 0; sub < 2; ++sub){
      f32x4 a0 = (f32x4){0.f,0.f,0.f,0.f};
      f32x4 a1 = (f32x4){0.f,0.f,0.f,0.f};
      const int gb = w * 64 + sub * 32 + mr;
      for (int k0 = 0; k0 < Kp; k0 += 32){
        half8 af = __builtin_bit_cast(half8, *(const short8*)&xs[mr][k0 + kc]);
        half8 b0 = __builtin_bit_cast(half8, *(const short8*)(Wb + (long)(gb     ) * Kp + k0 + kc));
        half8 b1 = __builtin_bit_cast(half8, *(const short8*)(Wb + (long)(gb + 16) * Kp + k0 + kc));
        a0 = __builtin_amdgcn_mfma_f32_16x16x32_f16(af, b0, a0, 0, 0, 0);
        a1 = __builtin_amdgcn_mfma_f32_16x16x32_f16(af, b1, a1, 0, 0, 0);
      }
      const int sr_ = (l >> 4) * 4;
      #pragma unroll
      for (int r = 0; r < 4; ++r){
        ps[sr_ + r][gb     ] = f2h(a0[r] + bias[gb     ]);
        ps[sr_ + r][gb + 16] = f2h(a1[r] + bias[gb + 16]);
      }
    }
    __syncthreads();                         // ps ready
    // ---- phase C: serial recurrence (1 gate row / thread)
    const int smax = min(TS, end - tile);
    for (int s = 0; s < smax; ++s){
      float pv = h2f(ps[s][G * 256 + u]);
      const int4* q1v = (const int4*)hq1;
      const int4* q2v = (const int4*)hq2;
      int A0 = 0, B0 = 0, C0 = 0;
      #pragma unroll
      for (int mm = 0; mm < 16; ++mm){
        int4 qa = q1v[mm];
        int4 qb = q2v[mm];
        A0 = sdot4(qa.x, p1r[4*mm+0], A0); A0 = sdot4(qa.y, p1r[4*mm+1], A0);
        A0 = sdot4(qa.z, p1r[4*mm+2], A0); A0 = sdot4(qa.w, p1r[4*mm+3], A0);
        B0 = sdot4(qb.x, p1r[4*mm+0], B0); B0 = sdot4(qb.y, p1r[4*mm+1], B0);
        B0 = sdot4(qb.z, p1r[4*mm+2], B0); B0 = sdot4(qb.w, p1r[4*mm+3], B0);
        { int wA = p2r[2*mm], wB = p2r[2*mm+1];
          C0 = sdot4((wA << 4) & 0xf0f0f0f0, qa.x, C0);
          C0 = sdot4( wA       & 0xf0f0f0f0, qa.y, C0);
          C0 = sdot4((wB << 4) & 0xf0f0f0f0, qa.z, C0);
          C0 = sdot4( wB       & 0xf0f0f0f0, qa.w, C0); }
      }
      float z = pv + k1 * ((float)A0 + (float)B0 * (1.f/127.f) + (float)C0 * (1.f/256.f));
      zb[G][u] = z;
      __syncthreads();                       // zb ready; hq reads done
      if (t < 256){
        float ig = sigm(zb[0][t]), fg = sigm(zb[1][t]);
        float gg = tanh_(zb[2][t]), og = sigm(zb[3][t]);
        cst = fg * cst + ig * gg;
        float hh = og * tanh_(cst);
        int step = tile + s;
        if (step >= start) sout[(long)step * 256 + t] = f2h(hh);
        float h127 = hh * 127.f;
        int q1 = __float2int_rn(h127);
        int q2 = __float2int_rn((h127 - (float)q1) * 127.f);
        ((signed char*)hq1)[t] = (signed char)q1;
        ((signed char*)hq2)[t] = (signed char)q2;
      }
      __syncthreads();                       // hq ready for next step
    }
  }
}

// final: out[e] = hid[e] . lw2 + lb2   (wave per edge)
__global__ void k_final(const unsigned short* __restrict__ hid, const float* __restrict__ lw2,
                        const float* __restrict__ lb2, float* __restrict__ out){
  int wid = (blockIdx.x * blockDim.x + threadIdx.x) >> 6;
  int l = threadIdx.x & 63;
  int nw = (gridDim.x * blockDim.x) >> 6;
  for (int e = wid; e < NE; e += nw){
    float a = h2f(hid[(long)e * HD + l]) * lw2[l]
            + h2f(hid[(long)e * HD + 64 + l]) * lw2[64 + l];
    #pragma unroll
    for (int off = 32; off; off >>= 1) a += __shfl_down(a, off, 64);
    if (l == 0) out[e] = a + lb2[0];
  }
}

// ---------------- host ----------------
extern "C" void kernel_launch(void* const* d_in, const int* in_sizes, int n_in,
                              void* d_out, int out_size, void* d_ws, size_t ws_size,
                              hipStream_t stream) {
  const float* x    = (const float*)d_in[0];
  const int*   ei   = (const int*)d_in[1];
  const float* attr = (const float*)d_in[2];
  const float* W1   = (const float*)d_in[3];
  const float* b1   = (const float*)d_in[4];
  const float* g1   = (const float*)d_in[5];
  const float* be1  = (const float*)d_in[6];
  const float* rm1  = (const float*)d_in[7];
  const float* rv1  = (const float*)d_in[8];
  const float* W2   = (const float*)d_in[9];
  const float* b2   = (const float*)d_in[10];
  const float* g2   = (const float*)d_in[11];
  const float* be2  = (const float*)d_in[12];
  const float* rm2  = (const float*)d_in[13];
  const float* rv2  = (const float*)d_in[14];
  const float* Wih0 = (const float*)d_in[15];
  const float* Whh0 = (const float*)d_in[16];
  const float* bih0 = (const float*)d_in[17];
  const float* bhh0 = (const float*)d_in[18];
  const float* Wih1 = (const float*)d_in[19];
  const float* Whh1 = (const float*)d_in[20];
  const float* bih1 = (const float*)d_in[21];
  const float* bhh1 = (const float*)d_in[22];
  const float* lw1  = (const float*)d_in[23];
  const float* lb1  = (const float*)d_in[24];
  const float* lw2  = (const float*)d_in[25];
  const float* lb2  = (const float*)d_in[26];
  const int* row = ei;
  const int* col = ei + NE;
  float* out = (float*)d_out;
  (void)in_sizes; (void)n_in; (void)out_size;

  // ---- workspace carve (~107 MB total) ----
  char* p0 = (char*)d_ws;
  char* p = p0;
  auto take = [&](size_t bytes)->char*{
    char* r = p; p += (bytes + 255) & ~(size_t)255; return r;
  };
  int*   wp1_0 = (int*)take((size_t)64 * G4 * 4);
  int*   wp2_0 = (int*)take((size_t)32 * G4 * 4);
  float* sr0   = (float*)take((size_t)G4 * 4);
  int*   wp1_1 = (int*)take((size_t)64 * G4 * 4);
  int*   wp2_1 = (int*)take((size_t)32 * G4 * 4);
  float* sr1   = (float*)take((size_t)G4 * 4);
  float* bias0 = (float*)take((size_t)G4 * 4);
  float* bias1 = (float*)take((size_t)G4 * 4);
  unsigned short* Wb0  = (unsigned short*)take((size_t)G4 * KP0 * 2);
  unsigned short* Wb1  = (unsigned short*)take((size_t)G4 * 256 * 2);
  unsigned short* lw1T = (unsigned short*)take((size_t)128 * 256 * 2);
  unsigned short* h2h  = (unsigned short*)take((size_t)NN * HD * 2);
  unsigned short* s1   = (unsigned short*)take((size_t)MPAD * 256 * 2);
  unsigned short* s2   = (unsigned short*)take((size_t)MPAD * 256 * 2);
  size_t required = (size_t)(p - p0);
  unsigned short* hid = s1;          // s1 dead once fscan1 consumed it

  // GCN scratch aliases inside s2 (dead before fscan1 writes s2)
  char* q = (char*)s2;
  auto take2 = [&](size_t bytes)->char*{
    char* r = q; q += (bytes + 255) & ~(size_t)255; return r;
  };
  float* deg  = (float*)take2((size_t)NN * 4);
  float* sacc = (float*)take2((size_t)NN * 4);
  float* acc2 = (float*)take2((size_t)NN * HD * 4);
  size_t zfloats = (size_t)(q - (char*)deg) / 4;
  float* dinv = (float*)take2((size_t)NN * 4);
  float* h1   = (float*)take2((size_t)NN * HD * 4);
  float* lin2 = (float*)take2((size_t)NN * HD * 4);

  if (ws_size < required){
    k_zero<<<256, 256, 0, stream>>>(out, (long)NE);
    return;
  }

  // --- GCN ---
  k_zero<<<2048, 256, 0, stream>>>(deg, (long)zfloats);
  k_deg<<<(NE + 255) / 256, 256, 0, stream>>>(col, deg);
  k_dinv<<<(NN + 255) / 256, 256, 0, stream>>>(deg, dinv);
  k_gcn1<<<(NE + NN + 255) / 256, 256, 0, stream>>>(row, col, x, dinv, sacc);
  k_h1<<<(NN * HD) / 256, 256, 0, stream>>>(sacc, W1, b1, g1, be1, rm1, rv1, h1);
  k_lin2<<<640, 128, 0, stream>>>(h1, W2, lin2);
  k_gcn2<<<4096, 256, 0, stream>>>(row, col, dinv, lin2, acc2);
  k_h2<<<(NN * HD) / 256, 256, 0, stream>>>(acc2, lin2, dinv, b2, g2, be2, rm2, rv2, h2h);

  // --- weight packing / quantization ---
  k_packW<<<(G4 * KP0 + 255) / 256, 256, 0, stream>>>(Wih0, G4, KIN0, KP0, Wb0);
  k_bias<<<4, 256, 0, stream>>>(bih0, bhh0, bias0, G4);
  k_packW<<<(G4 * 256 + 255) / 256, 256, 0, stream>>>(Wih1, G4, 256, 256, Wb1);
  k_bias<<<4, 256, 0, stream>>>(bih1, bhh1, bias1, G4);
  k_packlw1<<<(128 * 256) / 256, 256, 0, stream>>>(lw1, lw1T);
  k_quant<<<G4, 64, 0, stream>>>(Whh0, wp1_0, wp2_0, sr0);
  k_quant<<<G4, 64, 0, stream>>>(Whh1, wp1_1, wp2_1, sr1);

  // --- LSTM layers (fused GEMM+scan, 1024 threads, 1 gate/thread) ---
  k_fscan<<<CHUNKS, 1024, 0, stream>>>(h2h, row, col, attr, Wb0, bias0, KP0, 0,
                                       wp1_0, wp2_0, sr0, s1);
  k_fscan<<<CHUNKS, 1024, 0, stream>>>(s1, nullptr, nullptr, nullptr, Wb1, bias1, 256, 1,
                                       wp1_1, wp2_1, sr1, s2);

  // --- MLP head ---
  k_gemm_bt<<<dim3(MPAD / 128, 1), 256, 0, stream>>>(s2, lw1T, lb1, hid, 256, HD, 1);
  k_final<<<512, 256, 0, stream>>>(hid, lw2, lb2, out);
}